// Round 1
// baseline (1095.095 us; speedup 1.0000x reference)
//
#include <hip/hip_runtime.h>
#include <hip/hip_bf16.h>

// MetaQDA MAP. D=640, C=64, N=1024, Q=2048, REG=0.3.
// Algorithmic restructure: sigma_c*denom = L L^T + U_c J_c U_c^T (rank 18)
//   => Woodbury: diff^T sigma_inv diff = denom*(||Linv diff||^2 - g^T Kinv g)
// Only inversions needed: Linv (triangular 640) + 64x (18x18).

#define D 640
#define C 64
#define NSUP 1024
#define Q 2048
#define KMAX 16
#define R18 18           // Woodbury rank: 1 (m) + 16 (x) + 1 (mu)
#define VROWS (C * R18)  // 1152
#define YROWS 3137       // 2048 Xq + 1024 X + 1 m + 64 mu

// ---------------- setup: class counts/index lists + scalars --------------
__global__ void k_setup(const int* __restrict__ y, const float* __restrict__ kappa,
                        const float* __restrict__ nu, const float* __restrict__ diag,
                        int* __restrict__ cnt, int* __restrict__ idx,
                        float* __restrict__ sc, float* __restrict__ rd) {
    __shared__ int lc[C];
    int tid = threadIdx.x;
    if (tid < C) lc[tid] = 0;
    __syncthreads();
    for (int n = tid; n < NSUP; n += 256) {
        int c = y[n];
        int k = atomicAdd(&lc[c], 1);
        if (k < KMAX) idx[c * KMAX + k] = n;
    }
    __syncthreads();
    // reciprocal of |diag| for the triangular solve
    for (int d = tid; d < D; d += 256) rd[d] = 1.0f / fabsf(diag[d]);
    if (tid < C) {
        int n = lc[tid]; if (n > KMAX) n = KMAX;
        cnt[tid] = n;
        float kap = fabsf(kappa[0]) + 1e-6f;
        float nuv = fmaxf(nu[0], (float)(D - 1) + 1e-6f);
        float Ncf = (float)n;
        sc[64 + tid]  = Ncf / (kap + Ncf);            // w_c
        sc[128 + tid] = nuv + Ncf + (float)(D + 2);   // denom_c
        sc[192 + tid] = -1.0f / (kap + Ncf);          // J^{-1} last diag
        if (tid == 0) { sc[0] = kap; sc[1] = nuv; }
    }
}

// ---------------- mu[c][d] = (1-w)*m + w*mean_c --------------------------
__global__ void k_mu(const float* __restrict__ X, const float* __restrict__ m,
                     const int* __restrict__ cnt, const int* __restrict__ idx,
                     const float* __restrict__ sc, float* __restrict__ mu) {
    int c = blockIdx.x;
    int d = blockIdx.y * 128 + threadIdx.x;
    int n = cnt[c];
    float s = 0.f;
    for (int k = 0; k < n; ++k) s += X[(size_t)idx[c * KMAX + k] * D + d];
    float w = sc[64 + c];
    float mean = (n > 0) ? s / (float)n : 0.f;
    mu[(size_t)c * D + d] = (1.f - w) * m[d] + w * mean;
}

// ---------------- Linv: one wave per column, z lane-distributed in regs --
__global__ void k_linv(const float* __restrict__ diag, const float* __restrict__ low,
                       const float* __restrict__ rd, float* __restrict__ Linv) {
    int wv = threadIdx.x >> 6, lane = threadIdx.x & 63;
    int j = blockIdx.x * 4 + wv;
    if (j >= D) return;
    float z[10];
#pragma unroll
    for (int r = 0; r < 10; ++r) z[r] = 0.f;
    int jr = j >> 6, jl = j & 63;
#pragma unroll
    for (int r = 0; r < 10; ++r)
        if (r == jr && lane == jl) z[r] = rd[j];
    for (int i = j + 1; i < D; ++i) {
        float s = 0.f;
#pragma unroll
        for (int r = 0; r < 10; ++r) {
            int k = r * 64 + lane;
            if (k >= j && k < i) s += low[(size_t)i * D + k] * z[r];
        }
#pragma unroll
        for (int off = 32; off; off >>= 1) s += __shfl_xor(s, off);
        float zi = -s * rd[i];
        int ir = i >> 6, il = i & 63;
#pragma unroll
        for (int r = 0; r < 10; ++r)
            if (r == ir && lane == il) z[r] = zi;
    }
#pragma unroll
    for (int r = 0; r < 10; ++r)
        Linv[(size_t)(r * 64 + lane) * D + j] = z[r];  // zeros above diagonal too
}

// ---------------- gather Ycat = [Xq; X; m; mu] ---------------------------
__global__ void k_gather_y(const float* __restrict__ Xq, const float* __restrict__ X,
                           const float* __restrict__ m, const float* __restrict__ mu,
                           float* __restrict__ Ycat) {
    int r = blockIdx.x;
    const float* src;
    if (r < Q) src = Xq + (size_t)r * D;
    else if (r < Q + NSUP) src = X + (size_t)(r - Q) * D;
    else if (r == Q + NSUP) src = m;
    else src = mu + (size_t)(r - (Q + NSUP + 1)) * D;
    for (int d = threadIdx.x; d < D; d += 256) Ycat[(size_t)r * D + d] = src[d];
}

// ---------------- generic f32 NT GEMM: Out[r][n] = sum_k A[r][k]*B[n][k] -
#define BM 64
#define BN 64
#define BKK 16
__global__ void k_gemm_nt(const float* __restrict__ A, const float* __restrict__ B,
                          float* __restrict__ Out, int M, int Nn) {
    __shared__ __align__(16) float As[BKK][BM + 4];
    __shared__ __align__(16) float Bs[BKK][BN + 4];
    int tid = threadIdx.x;
    int tx = tid & 15, ty = tid >> 4;
    int rowBase = blockIdx.y * BM, colBase = blockIdx.x * BN;
    float acc[4][4] = {};
    for (int kk = 0; kk < D; kk += BKK) {
        __syncthreads();
        for (int i = tid; i < BM * BKK; i += 256) {
            int mm = i >> 4, k = i & 15;
            int gr = rowBase + mm;
            As[k][mm] = (gr < M) ? A[(size_t)gr * D + kk + k] : 0.f;
            int gc = colBase + mm;
            Bs[k][mm] = (gc < Nn) ? B[(size_t)gc * D + kk + k] : 0.f;
        }
        __syncthreads();
#pragma unroll
        for (int k = 0; k < BKK; ++k) {
            float4 av = *(const float4*)&As[k][ty * 4];
            float4 bv = *(const float4*)&Bs[k][tx * 4];
            float a0[4] = {av.x, av.y, av.z, av.w};
            float b0[4] = {bv.x, bv.y, bv.z, bv.w};
#pragma unroll
            for (int i2 = 0; i2 < 4; ++i2)
#pragma unroll
                for (int j2 = 0; j2 < 4; ++j2) acc[i2][j2] += a0[i2] * b0[j2];
        }
    }
#pragma unroll
    for (int i2 = 0; i2 < 4; ++i2) {
        int gr = rowBase + ty * 4 + i2;
        if (gr >= M) continue;
#pragma unroll
        for (int j2 = 0; j2 < 4; ++j2) {
            int gc = colBase + tx * 4 + j2;
            if (gc < Nn) Out[(size_t)gr * Nn + gc] = acc[i2][j2];
        }
    }
}

// ---------------- gather Vmat rows = tilde of [m, x_c1..16, mu_c] --------
__global__ void k_gather_v(const float* __restrict__ Yt, const int* __restrict__ cnt,
                           const int* __restrict__ idx, float* __restrict__ Vmat) {
    int row = blockIdx.x;           // 0..1151
    int c = row / R18, j = row % R18;
    const float* src = nullptr;
    if (j == 0) src = Yt + (size_t)(Q + NSUP) * D;                       // m~
    else if (j <= KMAX) {
        int k = j - 1;
        if (k < cnt[c]) src = Yt + (size_t)(Q + idx[c * KMAX + k]) * D;  // x~
    } else src = Yt + (size_t)(Q + NSUP + 1 + c) * D;                    // mu~
    for (int d = threadIdx.x; d < D; d += 256)
        Vmat[(size_t)row * D + d] = src ? src[d] : 0.f;
}

// ---------------- row norms (one wave per row) ---------------------------
__global__ void k_rownorm(const float* __restrict__ A, float* __restrict__ out, int M) {
    int gw = (blockIdx.x * 256 + threadIdx.x) >> 6;
    int lane = threadIdx.x & 63;
    if (gw >= M) return;
    const float* row = A + (size_t)gw * D;
    float s = 0.f;
    for (int d = lane; d < D; d += 64) { float v = row[d]; s += v * v; }
#pragma unroll
    for (int off = 32; off; off >>= 1) s += __shfl_xor(s, off);
    if (lane == 0) out[gw] = s;
}

// ---------------- per-class: Gram, K = J^{-1}+Gram, Kinv, h, btil, b0 ----
__global__ void k_class(const float* __restrict__ Vmat, const float* __restrict__ mu,
                        const float* __restrict__ sc, float* __restrict__ h,
                        float* __restrict__ btil, float* __restrict__ b0,
                        float* __restrict__ kinv) {
    __shared__ float sv[R18][D + 4];   // pad: stride 644 -> banks spread
    __shared__ float aug[R18][40];     // 18x36 augmented (+pad)
    __shared__ float red[256];
    __shared__ int piv;
    __shared__ float pv;
    int c = blockIdx.x, tid = threadIdx.x;
    for (int i = tid; i < R18 * D; i += 256) {
        int r = i / D, d = i % D;
        sv[r][d] = Vmat[(size_t)c * R18 * D + i];
    }
    __syncthreads();
    // Gram (upper triangle, mirrored)
    for (int p = tid; p < 171; p += 256) {
        int i = 0, rem = p;
        while (rem >= R18 - i) { rem -= R18 - i; ++i; }
        int j = i + rem;
        float s = 0.f;
        for (int d = 0; d < D; ++d) s += sv[i][d] * sv[j][d];
        aug[i][j] = s; aug[j][i] = s;
    }
    __syncthreads();
    if (tid < R18) h[c * R18 + tid] = aug[tid][R18 - 1];
    if (tid == 0) btil[c] = aug[R18 - 1][R18 - 1];
    // b0 = ||mu_c||^2
    float s0 = 0.f;
    for (int d = tid; d < D; d += 256) { float v = mu[(size_t)c * D + d]; s0 += v * v; }
    red[tid] = s0;
    __syncthreads();
    for (int st = 128; st; st >>= 1) { if (tid < st) red[tid] += red[tid + st]; __syncthreads(); }
    if (tid == 0) {
        b0[c] = red[0];
        // add J^{-1} diagonal
        aug[0][0] += 1.0f / sc[0];
        for (int t = 1; t <= KMAX; ++t) aug[t][t] += 1.0f;
        aug[R18 - 1][R18 - 1] += sc[192 + c];
    }
    for (int i = tid; i < R18 * R18; i += 256)
        aug[i / R18][R18 + i % R18] = (i / R18 == i % R18) ? 1.f : 0.f;
    __syncthreads();
    // Gauss-Jordan with partial pivoting
    for (int p = 0; p < R18; ++p) {
        if (tid == 0) {
            int bi = p; float bv = fabsf(aug[p][p]);
            for (int r = p + 1; r < R18; ++r) {
                float v = fabsf(aug[r][p]);
                if (v > bv) { bv = v; bi = r; }
            }
            piv = bi;
        }
        __syncthreads();
        if (piv != p && tid < 2 * R18) {
            float t = aug[p][tid]; aug[p][tid] = aug[piv][tid]; aug[piv][tid] = t;
        }
        __syncthreads();
        if (tid == 0) pv = aug[p][p];
        __syncthreads();
        if (tid < 2 * R18) aug[p][tid] /= pv;
        __syncthreads();
        if (tid < R18) red[tid] = aug[tid][p];
        __syncthreads();
        for (int i = tid; i < R18 * 2 * R18; i += 256) {
            int r = i / (2 * R18), col = i % (2 * R18);
            if (r != p) aug[r][col] -= red[r] * aug[p][col];
        }
        __syncthreads();
    }
    for (int i = tid; i < R18 * R18; i += 256)
        kinv[(size_t)c * R18 * R18 + i] = aug[i / R18][R18 + i % R18];
}

// ---------------- epilogue ----------------------------------------------
__global__ void k_epi(const float* __restrict__ G, const float* __restrict__ ip0,
                      const float* __restrict__ at, const float* __restrict__ a0,
                      const float* __restrict__ h, const float* __restrict__ btil,
                      const float* __restrict__ b0, const float* __restrict__ kinv,
                      const float* __restrict__ sc, float* __restrict__ out) {
    __shared__ float lk[R18 * R18], lh[R18];
    __shared__ float ldn, lbt, lb0;
    int c = blockIdx.x, tid = threadIdx.x;
    for (int i = tid; i < R18 * R18; i += 256) lk[i] = kinv[(size_t)c * R18 * R18 + i];
    if (tid < R18) lh[tid] = h[c * R18 + tid];
    if (tid == 0) { ldn = sc[128 + c]; lbt = btil[c]; lb0 = b0[c]; }
    __syncthreads();
    int q = blockIdx.y * 256 + tid;
    const float* Gr = G + (size_t)q * VROWS + c * R18;
    float g[R18];
#pragma unroll
    for (int j = 0; j < R18; ++j) g[j] = Gr[j];
    float ipt = g[R18 - 1];          // x~ . mu~
#pragma unroll
    for (int j = 0; j < R18; ++j) g[j] -= lh[j];
    float corr = 0.f;
#pragma unroll
    for (int i = 0; i < R18; ++i) {
        float s = 0.f;
#pragma unroll
        for (int j = 0; j < R18; ++j) s += lk[i * R18 + j] * g[j];
        corr += g[i] * s;
    }
    float tt = at[q] - 2.f * ipt + lbt;
    float t0 = a0[q] - 2.f * ip0[(size_t)q * C + c] + lb0;
    out[(size_t)q * C + c] = -(0.7f * ldn * (tt - corr) + 0.3f * t0);
}

extern "C" void kernel_launch(void* const* d_in, const int* in_sizes, int n_in,
                              void* d_out, int out_size, void* d_ws, size_t ws_size,
                              hipStream_t stream) {
    const float* X     = (const float*)d_in[0];
    const int*   y     = (const int*)d_in[1];
    const float* Xq    = (const float*)d_in[2];
    const float* m     = (const float*)d_in[3];
    const float* kappa = (const float*)d_in[4];
    const float* nu    = (const float*)d_in[5];
    const float* tdiag = (const float*)d_in[6];
    const float* tlow  = (const float*)d_in[7];
    float* out = (float*)d_out;

    // workspace layout (~31.5 MB)
    char* w = (char*)d_ws;
    auto alloc = [&](size_t bytes) {
        char* p = w;
        w += (bytes + 255) & ~(size_t)255;
        return p;
    };
    int*   cnt  = (int*)alloc(C * 4);
    int*   idx  = (int*)alloc(C * KMAX * 4);
    float* sc   = (float*)alloc(256 * 4);
    float* rd   = (float*)alloc(D * 4);
    float* mu   = (float*)alloc((size_t)C * D * 4);
    float* Ycat = (float*)alloc((size_t)3200 * D * 4);
    float* Yt   = (float*)alloc((size_t)3200 * D * 4);
    float* Linv = (float*)alloc((size_t)D * D * 4);
    float* Vmat = (float*)alloc((size_t)VROWS * D * 4);
    float* G    = (float*)alloc((size_t)Q * VROWS * 4);
    float* ip0  = (float*)alloc((size_t)Q * C * 4);
    float* at   = (float*)alloc(Q * 4);
    float* a0   = (float*)alloc(Q * 4);
    float* h    = (float*)alloc(C * R18 * 4);
    float* btil = (float*)alloc(C * 4);
    float* b0   = (float*)alloc(C * 4);
    float* kinv = (float*)alloc((size_t)C * R18 * R18 * 4);

    k_setup<<<1, 256, 0, stream>>>(y, kappa, nu, tdiag, cnt, idx, sc, rd);
    k_mu<<<dim3(C, D / 128), 128, 0, stream>>>(X, m, cnt, idx, sc, mu);
    k_linv<<<D / 4, 256, 0, stream>>>(tdiag, tlow, rd, Linv);
    k_gather_y<<<YROWS, 256, 0, stream>>>(Xq, X, m, mu, Ycat);
    // tilde transform: Yt = Ycat * Linv^T
    k_gemm_nt<<<dim3(D / BN, (YROWS + BM - 1) / BM), 256, 0, stream>>>(Ycat, Linv, Yt, YROWS, D);
    k_gather_v<<<VROWS, 256, 0, stream>>>(Yt, cnt, idx, Vmat);
    k_rownorm<<<Q / 4, 256, 0, stream>>>(Yt, at, Q);    // ||x~q||^2
    k_rownorm<<<Q / 4, 256, 0, stream>>>(Ycat, a0, Q);  // ||xq||^2
    k_class<<<C, 256, 0, stream>>>(Vmat, mu, sc, h, btil, b0, kinv);
    // G[q][c*18+j] = x~q . V~_{c,j}
    k_gemm_nt<<<dim3(VROWS / BN, Q / BM), 256, 0, stream>>>(Yt, Vmat, G, Q, VROWS);
    // ip0[q][c] = xq . mu_c
    k_gemm_nt<<<dim3(C / BN, Q / BM), 256, 0, stream>>>(Ycat, mu, ip0, Q, C);
    k_epi<<<dim3(C, Q / 256), 256, 0, stream>>>(G, ip0, at, a0, h, btil, b0, kinv, sc, out);
}

// Round 2
// 506.521 us; speedup vs baseline: 2.1620x; 2.1620x over previous
//
#include <hip/hip_runtime.h>
#include <hip/hip_bf16.h>

// MetaQDA MAP. D=640, C=64, N=1024, Q=2048, REG=0.3.
// sigma_c*denom = L L^T + U_c J_c U_c^T (rank 18) => Woodbury.
// Round 2: replace explicit Linv (latency-bound, 700us) + Yt GEMM with
// blocked forward substitution (128-blocks): Dinv diag blocks + Lhat +
// left-looking sub steps. Halves the substitution FLOPs too.

#define D 640
#define C 64
#define NSUP 1024
#define Q 2048
#define KMAX 16
#define R18 18           // Woodbury rank: 1 (m) + 16 (x) + 1 (mu)
#define VROWS (C * R18)  // 1152
#define YROWS 3137       // 2048 Xq + 1024 X + 1 m + 64 mu

// ---------------- setup: class counts/index lists + scalars --------------
__global__ void k_setup(const int* __restrict__ y, const float* __restrict__ kappa,
                        const float* __restrict__ nu, const float* __restrict__ diag,
                        int* __restrict__ cnt, int* __restrict__ idx,
                        float* __restrict__ sc, float* __restrict__ rd) {
    __shared__ int lc[C];
    int tid = threadIdx.x;
    if (tid < C) lc[tid] = 0;
    __syncthreads();
    for (int n = tid; n < NSUP; n += 256) {
        int c = y[n];
        int k = atomicAdd(&lc[c], 1);
        if (k < KMAX) idx[c * KMAX + k] = n;
    }
    __syncthreads();
    for (int d = tid; d < D; d += 256) rd[d] = 1.0f / fabsf(diag[d]);
    if (tid < C) {
        int n = lc[tid]; if (n > KMAX) n = KMAX;
        cnt[tid] = n;
        float kap = fabsf(kappa[0]) + 1e-6f;
        float nuv = fmaxf(nu[0], (float)(D - 1) + 1e-6f);
        float Ncf = (float)n;
        sc[64 + tid]  = Ncf / (kap + Ncf);            // w_c
        sc[128 + tid] = nuv + Ncf + (float)(D + 2);   // denom_c
        sc[192 + tid] = -1.0f / (kap + Ncf);          // J^{-1} last diag
        if (tid == 0) { sc[0] = kap; sc[1] = nuv; }
    }
}

// ---------------- mu[c][d] = (1-w)*m + w*mean_c --------------------------
__global__ void k_mu(const float* __restrict__ X, const float* __restrict__ m,
                     const int* __restrict__ cnt, const int* __restrict__ idx,
                     const float* __restrict__ sc, float* __restrict__ mu) {
    int c = blockIdx.x;
    int d = blockIdx.y * 128 + threadIdx.x;
    int n = cnt[c];
    float s = 0.f;
    for (int k = 0; k < n; ++k) s += X[(size_t)idx[c * KMAX + k] * D + d];
    float w = sc[64 + c];
    float mean = (n > 0) ? s / (float)n : 0.f;
    mu[(size_t)c * D + d] = (1.f - w) * m[d] + w * mean;
}

// ---------------- Dinv: invert 5 diagonal 128x128 blocks -----------------
// Row-owner sweep: lane owns rows {lane, 64+lane}; per step only a shuffle
// + fma on the dependent chain. L block pre-scaled by rd and stored
// XOR-swizzled in LDS (column reads conflict-free, no padding needed).
__global__ void k_dinv(const float* __restrict__ tlow, const float* __restrict__ rd,
                       float* __restrict__ Dinv) {
    __shared__ float Lst[128 * 128];   // 64 KB: Lst[c][r] = rd_r * L[r][c], swizzled
    int tid = threadIdx.x;
    int b = blockIdx.x >> 5;                       // 5 blocks x 32 WGs
    int j = ((blockIdx.x & 31) << 2) + (tid >> 6); // column this wave solves
    int lane = tid & 63;
    int bB = b * 128;
    for (int e = tid; e < 128 * 128; e += 256) {
        int c = e & 127, r = e >> 7;
        float v;
        if (r == c) v = 1.0f;
        else if (r > c) v = rd[bB + r] * tlow[(size_t)(bB + r) * D + bB + c];
        else v = 0.f;
        Lst[c * 128 + (r ^ (c & 63))] = v;
    }
    __syncthreads();
    float rd0 = rd[bB + lane], rd1 = rd[bB + 64 + lane];
    float acc0 = 0.f, acc1 = 0.f, zz0 = 0.f, zz1 = 0.f;
    for (int i = j; i < 128; ++i) {
        int ri = i >> 6, il = i & 63;
        float av = (ri == 0) ? acc0 : acc1;
        float ai = __shfl(av, il);
        float zi = (i == j) ? __shfl((ri == 0) ? rd0 : rd1, il) : -ai;
        int sw = i & 63;
        float l0 = Lst[i * 128 + (lane ^ sw)];
        float l1 = Lst[i * 128 + 64 + (lane ^ sw)];
        if (lane > i) acc0 += l0 * zi;
        if (64 + lane > i) acc1 += l1 * zi;
        if (lane == i) zz0 = zi;
        if (64 + lane == i) zz1 = zi;
    }
    Dinv[(size_t)b * 16384 + (size_t)lane * 128 + j] = zz0;
    Dinv[(size_t)b * 16384 + (size_t)(64 + lane) * 128 + j] = zz1;
}

// ---------------- Lhat_ik = Dinv_i * L_ik (strict-lower blocks) ----------
__global__ void k_lhat(const float* __restrict__ tlow, const float* __restrict__ Dinv,
                       float* __restrict__ Lhat) {
    const int bi_tab[10] = {1, 2, 2, 3, 3, 3, 4, 4, 4, 4};
    const int bk_tab[10] = {0, 0, 1, 0, 1, 2, 0, 1, 2, 3};
    int p = blockIdx.y;
    int bi = bi_tab[p], bk = bk_tab[p];
    int tid = threadIdx.x;
    int c = tid & 127;
    int r = (blockIdx.x << 1) + (tid >> 7);
    const float* drow = Dinv + (size_t)bi * 16384 + (size_t)r * 128;
    const float* lcol = tlow + (size_t)(bi * 128) * D + bk * 128 + c;
    float s = 0.f;
#pragma unroll 4
    for (int t = 0; t < 128; ++t) s += drow[t] * lcol[(size_t)t * D];
    Lhat[(size_t)(bi * 128 + r) * D + bk * 128 + c] = s;
}

// ---------------- gather Ycat = [Xq; X; m; mu] ---------------------------
__global__ void k_gather_y(const float* __restrict__ Xq, const float* __restrict__ X,
                           const float* __restrict__ m, const float* __restrict__ mu,
                           float* __restrict__ Ycat) {
    int r = blockIdx.x;
    const float* src;
    if (r < Q) src = Xq + (size_t)r * D;
    else if (r < Q + NSUP) src = X + (size_t)(r - Q) * D;
    else if (r == Q + NSUP) src = m;
    else src = mu + (size_t)(r - (Q + NSUP + 1)) * D;
    for (int d = threadIdx.x; d < D; d += 256) Ycat[(size_t)r * D + d] = src[d];
}

// ---------------- Yt = blockdiag(Dinv) * Ycat ----------------------------
__global__ void k_dy(const float* __restrict__ Ycat, const float* __restrict__ Dinv,
                     float* __restrict__ Yt) {
    __shared__ __align__(16) float As[16][68];
    __shared__ __align__(16) float Bs[16][68];
    int tid = threadIdx.x;
    int tx = tid & 15, ty = tid >> 4;
    int n0 = blockIdx.x * 64;
    int b = n0 >> 7, nb = n0 & 127;
    int rowBase = blockIdx.y * 64;
    float acc[4][4] = {};
    for (int kk = 0; kk < 128; kk += 16) {
        __syncthreads();
        for (int i = tid; i < 64 * 16; i += 256) {
            int mm = i >> 4, k = i & 15;
            int gr = rowBase + mm;
            As[k][mm] = (gr < YROWS) ? Ycat[(size_t)gr * D + b * 128 + kk + k] : 0.f;
            Bs[k][mm] = Dinv[(size_t)b * 16384 + (size_t)(nb + mm) * 128 + kk + k];
        }
        __syncthreads();
#pragma unroll
        for (int k = 0; k < 16; ++k) {
            float4 av = *(const float4*)&As[k][ty * 4];
            float4 bv = *(const float4*)&Bs[k][tx * 4];
            float a0[4] = {av.x, av.y, av.z, av.w};
            float b0[4] = {bv.x, bv.y, bv.z, bv.w};
#pragma unroll
            for (int i2 = 0; i2 < 4; ++i2)
#pragma unroll
                for (int j2 = 0; j2 < 4; ++j2) acc[i2][j2] += a0[i2] * b0[j2];
        }
    }
#pragma unroll
    for (int i2 = 0; i2 < 4; ++i2) {
        int gr = rowBase + ty * 4 + i2;
        if (gr >= YROWS) continue;
#pragma unroll
        for (int j2 = 0; j2 < 4; ++j2)
            Yt[(size_t)gr * D + n0 + tx * 4 + j2] = acc[i2][j2];
    }
}

// ---------------- left-looking substitution step ib (1..4) ---------------
// Yt[:, ibB:ibB+128] -= Yt[:, 0:ibB] * Lhat[ibB:ibB+128, 0:ibB]^T
__global__ void k_sub(const float* __restrict__ Lhat, float* __restrict__ Yt, int ib) {
    __shared__ __align__(16) float As[16][68];
    __shared__ __align__(16) float Bs[16][36];
    int tid = threadIdx.x;
    int tx = tid & 7, ty = tid >> 3;    // 8x4 cols = 32, 32x2 rows = 64
    int K = ib << 7;
    int colBase = ib * 128 + blockIdx.x * 32;
    int rowBase = blockIdx.y * 64;
    float acc[2][4] = {};
    for (int kk = 0; kk < K; kk += 16) {
        __syncthreads();
        for (int i = tid; i < 64 * 16; i += 256) {
            int mm = i >> 4, k = i & 15;
            int gr = rowBase + mm;
            As[k][mm] = (gr < YROWS) ? Yt[(size_t)gr * D + kk + k] : 0.f;
        }
        for (int i = tid; i < 32 * 16; i += 256) {
            int mm = i >> 4, k = i & 15;
            Bs[k][mm] = Lhat[(size_t)(colBase + mm) * D + kk + k];
        }
        __syncthreads();
#pragma unroll
        for (int k = 0; k < 16; ++k) {
            float a0 = As[k][ty * 2], a1 = As[k][ty * 2 + 1];
            float4 bv = *(const float4*)&Bs[k][tx * 4];
            float bb[4] = {bv.x, bv.y, bv.z, bv.w};
#pragma unroll
            for (int j2 = 0; j2 < 4; ++j2) {
                acc[0][j2] += a0 * bb[j2];
                acc[1][j2] += a1 * bb[j2];
            }
        }
    }
#pragma unroll
    for (int i2 = 0; i2 < 2; ++i2) {
        int gr = rowBase + ty * 2 + i2;
        if (gr >= YROWS) continue;
#pragma unroll
        for (int j2 = 0; j2 < 4; ++j2) {
            size_t a = (size_t)gr * D + colBase + tx * 4 + j2;
            Yt[a] = Yt[a] - acc[i2][j2];
        }
    }
}

// ---------------- generic f32 NT GEMM: Out[r][n] = sum_k A[r][k]*B[n][k] -
#define BM 64
#define BN 64
#define BKK 16
__global__ void k_gemm_nt(const float* __restrict__ A, const float* __restrict__ B,
                          float* __restrict__ Out, int M, int Nn) {
    __shared__ __align__(16) float As[BKK][BM + 4];
    __shared__ __align__(16) float Bs[BKK][BN + 4];
    int tid = threadIdx.x;
    int tx = tid & 15, ty = tid >> 4;
    int rowBase = blockIdx.y * BM, colBase = blockIdx.x * BN;
    float acc[4][4] = {};
    for (int kk = 0; kk < D; kk += BKK) {
        __syncthreads();
        for (int i = tid; i < BM * BKK; i += 256) {
            int mm = i >> 4, k = i & 15;
            int gr = rowBase + mm;
            As[k][mm] = (gr < M) ? A[(size_t)gr * D + kk + k] : 0.f;
            int gc = colBase + mm;
            Bs[k][mm] = (gc < Nn) ? B[(size_t)gc * D + kk + k] : 0.f;
        }
        __syncthreads();
#pragma unroll
        for (int k = 0; k < BKK; ++k) {
            float4 av = *(const float4*)&As[k][ty * 4];
            float4 bv = *(const float4*)&Bs[k][tx * 4];
            float a0[4] = {av.x, av.y, av.z, av.w};
            float b0[4] = {bv.x, bv.y, bv.z, bv.w};
#pragma unroll
            for (int i2 = 0; i2 < 4; ++i2)
#pragma unroll
                for (int j2 = 0; j2 < 4; ++j2) acc[i2][j2] += a0[i2] * b0[j2];
        }
    }
#pragma unroll
    for (int i2 = 0; i2 < 4; ++i2) {
        int gr = rowBase + ty * 4 + i2;
        if (gr >= M) continue;
#pragma unroll
        for (int j2 = 0; j2 < 4; ++j2) {
            int gc = colBase + tx * 4 + j2;
            if (gc < Nn) Out[(size_t)gr * Nn + gc] = acc[i2][j2];
        }
    }
}

// ---------------- gather Vmat rows = tilde of [m, x_c1..16, mu_c] --------
__global__ void k_gather_v(const float* __restrict__ Yt, const int* __restrict__ cnt,
                           const int* __restrict__ idx, float* __restrict__ Vmat) {
    int row = blockIdx.x;           // 0..1151
    int c = row / R18, j = row % R18;
    const float* src = nullptr;
    if (j == 0) src = Yt + (size_t)(Q + NSUP) * D;                       // m~
    else if (j <= KMAX) {
        int k = j - 1;
        if (k < cnt[c]) src = Yt + (size_t)(Q + idx[c * KMAX + k]) * D;  // x~
    } else src = Yt + (size_t)(Q + NSUP + 1 + c) * D;                    // mu~
    for (int d = threadIdx.x; d < D; d += 256)
        Vmat[(size_t)row * D + d] = src ? src[d] : 0.f;
}

// ---------------- row norms (one wave per row) ---------------------------
__global__ void k_rownorm(const float* __restrict__ A, float* __restrict__ out, int M) {
    int gw = (blockIdx.x * 256 + threadIdx.x) >> 6;
    int lane = threadIdx.x & 63;
    if (gw >= M) return;
    const float* row = A + (size_t)gw * D;
    float s = 0.f;
    for (int d = lane; d < D; d += 64) { float v = row[d]; s += v * v; }
#pragma unroll
    for (int off = 32; off; off >>= 1) s += __shfl_xor(s, off);
    if (lane == 0) out[gw] = s;
}

// ---------------- per-class: Gram, K = J^{-1}+Gram, Kinv, h, btil, b0 ----
__global__ void k_class(const float* __restrict__ Vmat, const float* __restrict__ mu,
                        const float* __restrict__ sc, float* __restrict__ h,
                        float* __restrict__ btil, float* __restrict__ b0,
                        float* __restrict__ kinv) {
    __shared__ float sv[R18][D + 4];
    __shared__ float aug[R18][40];
    __shared__ float red[256];
    __shared__ int piv;
    __shared__ float pv;
    int c = blockIdx.x, tid = threadIdx.x;
    for (int i = tid; i < R18 * D; i += 256) {
        int r = i / D, d = i % D;
        sv[r][d] = Vmat[(size_t)c * R18 * D + i];
    }
    __syncthreads();
    for (int p = tid; p < 171; p += 256) {
        int i = 0, rem = p;
        while (rem >= R18 - i) { rem -= R18 - i; ++i; }
        int j = i + rem;
        float s = 0.f;
        for (int d = 0; d < D; ++d) s += sv[i][d] * sv[j][d];
        aug[i][j] = s; aug[j][i] = s;
    }
    __syncthreads();
    if (tid < R18) h[c * R18 + tid] = aug[tid][R18 - 1];
    if (tid == 0) btil[c] = aug[R18 - 1][R18 - 1];
    float s0 = 0.f;
    for (int d = tid; d < D; d += 256) { float v = mu[(size_t)c * D + d]; s0 += v * v; }
    red[tid] = s0;
    __syncthreads();
    for (int st = 128; st; st >>= 1) { if (tid < st) red[tid] += red[tid + st]; __syncthreads(); }
    if (tid == 0) {
        b0[c] = red[0];
        aug[0][0] += 1.0f / sc[0];
        for (int t = 1; t <= KMAX; ++t) aug[t][t] += 1.0f;
        aug[R18 - 1][R18 - 1] += sc[192 + c];
    }
    for (int i = tid; i < R18 * R18; i += 256)
        aug[i / R18][R18 + i % R18] = (i / R18 == i % R18) ? 1.f : 0.f;
    __syncthreads();
    for (int p = 0; p < R18; ++p) {
        if (tid == 0) {
            int bi = p; float bv = fabsf(aug[p][p]);
            for (int r = p + 1; r < R18; ++r) {
                float v = fabsf(aug[r][p]);
                if (v > bv) { bv = v; bi = r; }
            }
            piv = bi;
        }
        __syncthreads();
        if (piv != p && tid < 2 * R18) {
            float t = aug[p][tid]; aug[p][tid] = aug[piv][tid]; aug[piv][tid] = t;
        }
        __syncthreads();
        if (tid == 0) pv = aug[p][p];
        __syncthreads();
        if (tid < 2 * R18) aug[p][tid] /= pv;
        __syncthreads();
        if (tid < R18) red[tid] = aug[tid][p];
        __syncthreads();
        for (int i = tid; i < R18 * 2 * R18; i += 256) {
            int r = i / (2 * R18), col = i % (2 * R18);
            if (r != p) aug[r][col] -= red[r] * aug[p][col];
        }
        __syncthreads();
    }
    for (int i = tid; i < R18 * R18; i += 256)
        kinv[(size_t)c * R18 * R18 + i] = aug[i / R18][R18 + i % R18];
}

// ---------------- epilogue ----------------------------------------------
__global__ void k_epi(const float* __restrict__ G, const float* __restrict__ ip0,
                      const float* __restrict__ at, const float* __restrict__ a0,
                      const float* __restrict__ h, const float* __restrict__ btil,
                      const float* __restrict__ b0, const float* __restrict__ kinv,
                      const float* __restrict__ sc, float* __restrict__ out) {
    __shared__ float lk[R18 * R18], lh[R18];
    __shared__ float ldn, lbt, lb0;
    int c = blockIdx.x, tid = threadIdx.x;
    for (int i = tid; i < R18 * R18; i += 256) lk[i] = kinv[(size_t)c * R18 * R18 + i];
    if (tid < R18) lh[tid] = h[c * R18 + tid];
    if (tid == 0) { ldn = sc[128 + c]; lbt = btil[c]; lb0 = b0[c]; }
    __syncthreads();
    int q = blockIdx.y * 256 + tid;
    const float* Gr = G + (size_t)q * VROWS + c * R18;
    float g[R18];
#pragma unroll
    for (int j = 0; j < R18; ++j) g[j] = Gr[j];
    float ipt = g[R18 - 1];
#pragma unroll
    for (int j = 0; j < R18; ++j) g[j] -= lh[j];
    float corr = 0.f;
#pragma unroll
    for (int i = 0; i < R18; ++i) {
        float s = 0.f;
#pragma unroll
        for (int j = 0; j < R18; ++j) s += lk[i * R18 + j] * g[j];
        corr += g[i] * s;
    }
    float tt = at[q] - 2.f * ipt + lbt;
    float t0 = a0[q] - 2.f * ip0[(size_t)q * C + c] + lb0;
    out[(size_t)q * C + c] = -(0.7f * ldn * (tt - corr) + 0.3f * t0);
}

extern "C" void kernel_launch(void* const* d_in, const int* in_sizes, int n_in,
                              void* d_out, int out_size, void* d_ws, size_t ws_size,
                              hipStream_t stream) {
    const float* X     = (const float*)d_in[0];
    const int*   y     = (const int*)d_in[1];
    const float* Xq    = (const float*)d_in[2];
    const float* m     = (const float*)d_in[3];
    const float* kappa = (const float*)d_in[4];
    const float* nu    = (const float*)d_in[5];
    const float* tdiag = (const float*)d_in[6];
    const float* tlow  = (const float*)d_in[7];
    float* out = (float*)d_out;

    char* w = (char*)d_ws;
    auto alloc = [&](size_t bytes) {
        char* p = w;
        w += (bytes + 255) & ~(size_t)255;
        return p;
    };
    int*   cnt  = (int*)alloc(C * 4);
    int*   idx  = (int*)alloc(C * KMAX * 4);
    float* sc   = (float*)alloc(256 * 4);
    float* rd   = (float*)alloc(D * 4);
    float* mu   = (float*)alloc((size_t)C * D * 4);
    float* Ycat = (float*)alloc((size_t)YROWS * D * 4);
    float* Yt   = (float*)alloc((size_t)YROWS * D * 4);
    float* Dinv = (float*)alloc((size_t)5 * 128 * 128 * 4);
    float* Lhat = (float*)alloc((size_t)D * D * 4);
    float* Vmat = (float*)alloc((size_t)VROWS * D * 4);
    float* G    = (float*)alloc((size_t)Q * VROWS * 4);
    float* ip0  = (float*)alloc((size_t)Q * C * 4);
    float* at   = (float*)alloc(Q * 4);
    float* a0   = (float*)alloc(Q * 4);
    float* h    = (float*)alloc(C * R18 * 4);
    float* btil = (float*)alloc(C * 4);
    float* b0   = (float*)alloc(C * 4);
    float* kinv = (float*)alloc((size_t)C * R18 * R18 * 4);

    k_setup<<<1, 256, 0, stream>>>(y, kappa, nu, tdiag, cnt, idx, sc, rd);
    k_mu<<<dim3(C, D / 128), 128, 0, stream>>>(X, m, cnt, idx, sc, mu);
    k_dinv<<<160, 256, 0, stream>>>(tlow, rd, Dinv);
    k_lhat<<<dim3(64, 10), 256, 0, stream>>>(tlow, Dinv, Lhat);
    k_gather_y<<<YROWS, 256, 0, stream>>>(Xq, X, m, mu, Ycat);
    k_dy<<<dim3(10, (YROWS + 63) / 64), 256, 0, stream>>>(Ycat, Dinv, Yt);
    for (int ib = 1; ib < 5; ++ib)
        k_sub<<<dim3(4, (YROWS + 63) / 64), 256, 0, stream>>>(Lhat, Yt, ib);
    k_gather_v<<<VROWS, 256, 0, stream>>>(Yt, cnt, idx, Vmat);
    k_rownorm<<<Q / 4, 256, 0, stream>>>(Yt, at, Q);
    k_rownorm<<<Q / 4, 256, 0, stream>>>(Ycat, a0, Q);
    k_class<<<C, 256, 0, stream>>>(Vmat, mu, sc, h, btil, b0, kinv);
    k_gemm_nt<<<dim3(VROWS / BN, Q / BM), 256, 0, stream>>>(Yt, Vmat, G, Q, VROWS);
    k_gemm_nt<<<dim3(C / BN, Q / BM), 256, 0, stream>>>(Ycat, mu, ip0, Q, C);
    k_epi<<<dim3(C, Q / 256), 256, 0, stream>>>(G, ip0, at, a0, h, btil, b0, kinv, sc, out);
}